// Round 14
// baseline (263.193 us; speedup 1.0000x reference)
//
#include <hip/hip_runtime.h>
#include <cstdint>

static constexpr int T1   = 512;    // hash kernel block size (8 waves)
static constexpr int T2   = 256;    // select kernel block size
static constexpr int BS   = 4096;
static constexpr int C    = 16384;
static constexpr int D    = 128;
static constexpr int HALF = 2048;   // rows 0..2047 pair with rows 2048..4095
static constexpr int NPOS = 4;
static constexpr int NNEG = 20;
static constexpr int NSEL = 24;
static constexpr int QPT1 = 8;      // int4 quads per thread per row (32 cols)

// Pre-filter threshold: top 1/128 of u32 (~128 candidates/row, need <=24).
// Below-TH elements produce small nonzero "fake" comps (<= 32767) that are
// strictly below every real d>=1 candidate (>= 32768) and are never popped;
// selection stays exact (rebuild rescans true comps with no threshold).
static constexpr uint32_t TH = 0xFE000000u;
// comp32 + OFF64 == full-range 64-bit comp (exact: TH's low 9 bits are 0)
static constexpr uint64_t OFF64 = ((uint64_t)(TH >> 9)) << 14;

__device__ __forceinline__ uint32_t rotl32(uint32_t x, int r) {
  return __builtin_amdgcn_alignbit(x, x, 32 - r);   // 1 instr
}

static constexpr uint32_t KS1 = 42u;
static constexpr uint32_t KS2 = 0x1BD11BDAu ^ 42u;   // ks0 = 0

// ---- JAX threefry2x32 (20 rounds), key = PRNGKey(42) = [0, 42] ----
__device__ __forceinline__ void tf2x32(uint32_t x0, uint32_t x1,
                                       uint32_t& o0, uint32_t& o1) {
  x1 += KS1;
#define TFR(r) { x0 += x1; x1 = rotl32(x1, (r)); x1 ^= x0; }
  TFR(13) TFR(15) TFR(26) TFR(6)
  x0 += KS1; x1 += KS2 + 1u;
  TFR(17) TFR(29) TFR(16) TFR(24)
  x0 += KS2; x1 += 2u;
  TFR(13) TFR(15) TFR(26) TFR(6)
  x1 += KS1 + 3u;
  TFR(17) TFR(29) TFR(16) TFR(24)
  x0 += KS1; x1 += KS2 + 4u;
  TFR(13) TFR(15) TFR(26) TFR(6)
  x0 += KS2; x1 += 5u;
#undef TFR
  o0 = x0; o1 = x1;
}

// 8 independent chains, round-interleaved (ILP=8). Chains 0-3: quad j
// (counter n0+k), chains 4-7: quad j+1 (n1 = n0 + 2048, 512-thread stride).
__device__ __forceinline__ void tf8(uint32_t n0, uint32_t n1,
                                    uint32_t (&oa)[8], uint32_t (&ob)[8]) {
  uint32_t x0[8], x1[8];
#pragma unroll
  for (int k = 0; k < 8; ++k) {
    const uint32_t n = (k < 4) ? (n0 + k) : (n1 + (k - 4));
    x0[k] = n; x1[k] = n + (0x2000000u + KS1);
  }
#define R8(r) { _Pragma("unroll") \
  for (int k = 0; k < 8; ++k) { x0[k] += x1[k]; x1[k] = rotl32(x1[k], (r)); x1[k] ^= x0[k]; } }
#define INJ8(a0, a1) { _Pragma("unroll") \
  for (int k = 0; k < 8; ++k) { x0[k] += (a0); x1[k] += (a1); } }
  R8(13) R8(15) R8(26) R8(6)
  INJ8(KS1, KS2 + 1u)
  R8(17) R8(29) R8(16) R8(24)
  INJ8(KS2, 2u)
  R8(13) R8(15) R8(26) R8(6)
  INJ8(0u, KS1 + 3u)
  R8(17) R8(29) R8(16) R8(24)
  INJ8(KS1, KS2 + 4u)
  R8(13) R8(15) R8(26) R8(6)
  INJ8(KS2, 5u)
#undef R8
#undef INJ8
#pragma unroll
  for (int k = 0; k < 8; ++k) { oa[k] = x0[k]; ob[k] = x1[k]; }
}

// full-range 64-bit composite key (rebuild path): larger = better; equal bits
// -> smaller col wins (jax top_k tie-break). Unique per row.
__device__ __forceinline__ uint64_t mkcomp(uint32_t bits, int c) {
  return (((uint64_t)(bits >> 9) + 1ull) << 14) | (uint64_t)(16383 - c);
}

// 6-op thresholded insert. Identity (mod 2^32, TH low-9 bits = 0):
//   ((max(o,TH)-TH)>>9)<<14 + Ke == ((max(o,TH) & ~0x1FF) << 5) + Ke - (TH<<5)
// so with KeAdj = Ke + 0x40000000 (= Ke - (TH<<5 mod 2^32)) the comps are
// bit-identical to the round-13 7-op form. Below-TH -> comp = Ke (fake).
__device__ __forceinline__ void filt_ins(uint32_t o, uint32_t KeAdj,
                                         uint32_t& a, uint32_t& b) {
  const uint32_t m  = (o > TH) ? o : TH;           // v_max_u32
  const uint32_t m2 = m & 0xFFFFFE00u;             // v_and
  const uint32_t comp = (m2 << 5) + KeAdj;         // v_lshl_add
  const uint32_t lo = comp < a ? comp : a;         // v_min
  a = comp > a ? comp : a;                         // v_max
  b = lo > b ? lo : b;                             // v_max
}

// ---------------- kernel 1: labels + hash + per-thread top-2 ----------------
__global__ __launch_bounds__(T1) void hash_topk(
    const int* __restrict__ lab, uint4* __restrict__ cand,
    int4* __restrict__ posIdx, unsigned int* __restrict__ ticket) {
  __shared__ int posCnt[2];
  __shared__ int posBuf[2][4];
  const int tid = threadIdx.x;
  const int r = blockIdx.x;
  const int rbase = r * C;

  if (r == 0 && tid == 0) *ticket = 0u;   // reset last-block ticket each launch
  if (tid < 2) posCnt[tid] = 0;
  __syncthreads();

  const int4* labL4 = reinterpret_cast<const int4*>(lab + (size_t)rbase);
  const int4* labH4 = reinterpret_cast<const int4*>(lab + ((size_t)r + HALF) * C);
  uint32_t L0 = 0, L1 = 0, H0 = 0, H1 = 0;

#define CAP(V, S, CQ) \
  if (V.x | V.y | V.z | V.w) { \
    if (V.x) { int s = atomicAdd(&posCnt[S], 1); if (s < 4) posBuf[S][s] = (CQ); }     \
    if (V.y) { int s = atomicAdd(&posCnt[S], 1); if (s < 4) posBuf[S][s] = (CQ) + 1; } \
    if (V.z) { int s = atomicAdd(&posCnt[S], 1); if (s < 4) posBuf[S][s] = (CQ) + 2; } \
    if (V.w) { int s = atomicAdd(&posCnt[S], 1); if (s < 4) posBuf[S][s] = (CQ) + 3; } \
  }

#pragma unroll 1
  for (int j = 0; j < QPT1; j += 2) {
    // loads issued up-front; hash (~700 VALU) runs before CAP consumes them
    const int4 vL0 = labL4[j * T1 + tid];
    const int4 vL1 = labL4[(j + 1) * T1 + tid];
    const int4 vH0 = labH4[j * T1 + tid];
    const int4 vH1 = labH4[(j + 1) * T1 + tid];
    const int cq0 = (j * T1 + tid) << 2;          // quad j; quad j+1 at +2048
    uint32_t oa[8], ob[8];
    tf8((uint32_t)(rbase + cq0), (uint32_t)(rbase + cq0 + 2048), oa, ob);
    const uint32_t ka0 = (32767u + 0x40000000u) - (uint32_t)cq0;  // KeAdj
    const uint32_t ka1 = ka0 - 2048u;
#pragma unroll
    for (int k = 0; k < 4; ++k) {
      filt_ins(oa[k],     ka0 - (uint32_t)k, L0, L1);
      filt_ins(oa[4 + k], ka1 - (uint32_t)k, L0, L1);
      filt_ins(ob[k],     ka0 - (uint32_t)k, H0, H1);
      filt_ins(ob[4 + k], ka1 - (uint32_t)k, H0, H1);
    }
    CAP(vL0, 0, cq0) CAP(vL1, 0, cq0 + 2048)
    CAP(vH0, 1, cq0) CAP(vH1, 1, cq0 + 2048)
  }
#undef CAP

  uint4 st; st.x = L0; st.y = L1; st.z = H0; st.w = H1;
  cand[(size_t)r * T1 + tid] = st;
  __syncthreads();
  if (tid < 2) {   // sort 4 positive cols ascending (jax top_k tie order)
    int a = posBuf[tid][0], b2 = posBuf[tid][1], c2 = posBuf[tid][2], d = posBuf[tid][3];
#define CSW(x, y) if (x > y) { int t_ = x; x = y; y = t_; }
    CSW(a, b2) CSW(c2, d) CSW(a, c2) CSW(b2, d) CSW(b2, c2)
#undef CSW
    int4 o; o.x = a; o.y = b2; o.z = c2; o.w = d;
    posIdx[r * 2 + tid] = o;
  }
}

// Wave-synchronous top-20-negative selection over 512 depth-2 lists
// (8 lists per lane, statically indexed). Positives consumed-but-skipped.
// On list exhaustion (promotion wrote nxt=0), lanes 0..31 cooperatively
// rescan that thread's 32 columns (true comps, no threshold).
__device__ __forceinline__ void wave_select8(
    const uint32_t (*cd)[2], int* selX, int rbase, int hi, int4 p) {
  const int lane = threadIdx.x & 63;
  const int tb = lane << 3;
  const uint64_t laneu = (uint64_t)lane;
  uint64_t cur[8], nxt[8];
#pragma unroll
  for (int s = 0; s < 8; ++s) {
    cur[s] = (uint64_t)cd[tb + s][0] + OFF64;
    nxt[s] = (uint64_t)cd[tb + s][1] + OFF64;
  }
  int got = 0;
#pragma unroll 1
  for (int it = 0; it < NSEL && got < NNEG; ++it) {
    uint64_t m = 0;
#pragma unroll
    for (int s = 0; s < 8; ++s) {
      const uint64_t t = (cur[s] << 9) | ((uint64_t)s << 6) | laneu;
      if (t > m) m = t;
    }
#pragma unroll
    for (int o = 32; o; o >>= 1) {
      const uint64_t y = (uint64_t)__shfl_xor((unsigned long long)m, o, 64);
      if (y > m) m = y;
    }
    const int col = 16383 - (int)((m >> 9) & 0x3FFFull);
    const bool isPos = (col == p.x) || (col == p.y) || (col == p.z) || (col == p.w);
    if (!isPos) {
      if (lane == 0) selX[NPOS + got] = col;
      ++got;
    }
    const int owner = (int)(m & 63ull);
    const int slot  = (int)((m >> 6) & 7ull);
    const uint64_t bound = m >> 9;
    uint64_t mynxt = 0;
#pragma unroll
    for (int s = 0; s < 8; ++s) mynxt = (slot == s) ? nxt[s] : mynxt;
    const uint64_t ownnxt =
        (uint64_t)__shfl((unsigned long long)mynxt, owner, 64);
    uint64_t newv;
    if (ownnxt) {                        // wave-uniform: promote cached nxt
      newv = ownnxt;
    } else {                             // cooperative rebuild (rare)
      const int thr = (owner << 3) | slot;
      uint64_t v = 0;
      if (lane < 32) {
        const int col2 = ((lane >> 2) << 11) + (thr << 2) + (lane & 3);
        uint32_t o0, o1;
        tf2x32((uint32_t)(rbase + col2), (uint32_t)(rbase + col2) + 0x2000000u, o0, o1);
        v = mkcomp(hi ? o1 : o0, col2);
        if (v >= bound) v = 0;
      }
#pragma unroll
      for (int o = 32; o; o >>= 1) {
        const uint64_t y = (uint64_t)__shfl_xor((unsigned long long)v, o, 64);
        if (y > v) v = y;
      }
      newv = v;
    }
    if (lane == owner) {
#pragma unroll
      for (int s = 0; s < 8; ++s)
        if (slot == s) { cur[s] = newv; nxt[s] = 0; }
    }
  }
}

// -------- kernel 2: select + sim + BCE (+ last-block final reduction) -------
__global__ __launch_bounds__(T2, 2) void select_sim(
    const float* __restrict__ feat, const float* __restrict__ proto,
    const uint4* __restrict__ cand, const int4* __restrict__ posIdx,
    float* __restrict__ row_ws, unsigned int* __restrict__ ticket,
    float* __restrict__ out) {
  __shared__ uint32_t candL[T1][2];
  __shared__ uint32_t candH[T1][2];
  __shared__ int selL[NSEL], selH[NSEL];
  __shared__ float ffL[D], ffH[D];
  __shared__ float normL, normH;
  __shared__ float bces[2 * NSEL];
  __shared__ int lastFlag;

  const int tid = threadIdx.x;
  const int r = blockIdx.x;
  const int rbase = r * C;

  const uint4 cd0 = cand[(size_t)r * T1 + tid];
  const uint4 cd1 = cand[(size_t)r * T1 + T2 + tid];
  candL[tid][0] = cd0.x;      candL[tid][1] = cd0.y;
  candH[tid][0] = cd0.z;      candH[tid][1] = cd0.w;
  candL[T2 + tid][0] = cd1.x; candL[T2 + tid][1] = cd1.y;
  candH[T2 + tid][0] = cd1.z; candH[T2 + tid][1] = cd1.w;
  const int4 pL = posIdx[r * 2];
  const int4 pH = posIdx[r * 2 + 1];
  if (tid == 0) { selL[0] = pL.x; selL[1] = pL.y; selL[2] = pL.z; selL[3] = pL.w; }
  if (tid == 1) { selH[0] = pH.x; selH[1] = pH.y; selH[2] = pH.z; selH[3] = pH.w; }
  __syncthreads();

  const int wv = tid >> 6;
  if (wv == 0) {
    wave_select8(candL, selL, rbase, 0, pL);
  } else if (wv == 1) {
    wave_select8(candH, selH, rbase, 1, pH);
  } else if (wv == 2) {
    const int l = tid & 63;
    const float a = feat[(size_t)r * D + l];
    const float b = feat[(size_t)r * D + 64 + l];
    ffL[l] = a; ffL[64 + l] = b;
    float s = a * a + b * b;
#pragma unroll
    for (int o = 32; o; o >>= 1) s += __shfl_xor(s, o, 64);
    if (l == 0) normL = s;
  } else {
    const int l = tid & 63;
    const float a = feat[((size_t)r + HALF) * D + l];
    const float b = feat[((size_t)r + HALF) * D + 64 + l];
    ffH[l] = a; ffH[64 + l] = b;
    float s = a * a + b * b;
#pragma unroll
    for (int o = 32; o; o >>= 1) s += __shfl_xor(s, o, 64);
    if (l == 0) normH = s;
  }
  __syncthreads();

  if (tid < 4 * 2 * NSEL) {
    const int ci = tid >> 2;            // 0..47
    const int k  = tid & 3;
    const bool isH = ci >= NSEL;
    const int g = isH ? ci - NSEL : ci;
    const int c = isH ? selH[g] : selL[g];
    const float* ff = isH ? ffH : ffL;
    const float4* pc = reinterpret_cast<const float4*>(proto + (size_t)c * D);
    float fp = 0.f, pp = 0.f;
#pragma unroll
    for (int qq = 0; qq < 8; ++qq) {
      const float4 pv = pc[k * 8 + qq];
      const int d0 = k * 32 + qq * 4;
      fp += ff[d0] * pv.x + ff[d0 + 1] * pv.y + ff[d0 + 2] * pv.z + ff[d0 + 3] * pv.w;
      pp += pv.x * pv.x + pv.y * pv.y + pv.z * pv.z + pv.w * pv.w;
    }
    fp += __shfl_xor(fp, 1, 64); pp += __shfl_xor(pp, 1, 64);
    fp += __shfl_xor(fp, 2, 64); pp += __shfl_xor(pp, 2, 64);
    if (k == 0) {
      const float x = (isH ? normH : normL) * pp;
      float rn = rsqrtf(x);
      rn = rn * (1.5f - 0.5f * x * rn * rn);   // 1 NR step for accuracy
      const float l = fp * rn * 10.0f;          // /TEMP, TEMP=0.1
      const float tgt = (g < NPOS) ? 0.25f : 0.0f;
      bces[ci] = fmaxf(l, 0.f) - l * tgt + __logf(1.0f + __expf(-fabsf(l)));
    }
  }
  __syncthreads();
  if (tid < 2) {
    float s = 0.f;
    const int base = tid * NSEL;
#pragma unroll
    for (int i = 0; i < NSEL; ++i) s += bces[base + i];
    row_ws[tid ? (r + HALF) : r] = s * (1.0f / NSEL);
  }

  // ---- last block performs the final deterministic reduction ----
  __threadfence();                       // row_ws visible device-wide
  __syncthreads();
  if (tid == 0) lastFlag = (atomicAdd(ticket, 1u) == (unsigned)(HALF - 1));
  __syncthreads();
  if (lastFlag) {
    __threadfence();                     // acquire all other blocks' row_ws
    __shared__ float red[T2];
    float s = 0.f;
#pragma unroll
    for (int j = 0; j < BS / T2; ++j) s += row_ws[j * T2 + tid];
    red[tid] = s;
    __syncthreads();
    for (int o = T2 / 2; o > 0; o >>= 1) {
      if (tid < o) red[tid] += red[tid + o];
      __syncthreads();
    }
    if (tid == 0) out[0] = red[0] * (1.0f / BS);
  }
}

extern "C" void kernel_launch(void* const* d_in, const int* in_sizes, int n_in,
                              void* d_out, int out_size, void* d_ws, size_t ws_size,
                              hipStream_t stream) {
  (void)in_sizes; (void)n_in; (void)out_size; (void)ws_size;
  const float* feat  = (const float*)d_in[0];
  const float* proto = (const float*)d_in[1];
  const int*   lab   = (const int*)d_in[2];
  float* out = (float*)d_out;
  // ws layout: [0,16K): row_ws float[4096]; [16K,144K): posIdx int4[4096];
  //            [144K,144K+4): ticket u32; [256K,256K+16M): cand uint4[2048*512]
  float* ws     = (float*)d_ws;
  int4*  posIdx = (int4*)((char*)d_ws + (16 << 10));
  unsigned int* ticket = (unsigned int*)((char*)d_ws + (144 << 10));
  uint4* cand   = (uint4*)((char*)d_ws + (256 << 10));

  hash_topk <<<dim3(HALF), dim3(T1), 0, stream>>>(lab, cand, posIdx, ticket);
  select_sim<<<dim3(HALF), dim3(T2), 0, stream>>>(feat, proto, cand, posIdx,
                                                  ws, ticket, out);
}

// Round 15
// 113.789 us; speedup vs baseline: 2.3130x; 2.3130x over previous
//
#include <hip/hip_runtime.h>
#include <cstdint>

static constexpr int T1   = 512;    // fused kernel block size (8 waves)
static constexpr int T2   = 256;    // reduce kernel block size
static constexpr int BS   = 4096;
static constexpr int C    = 16384;
static constexpr int D    = 128;
static constexpr int HALF = 2048;   // rows 0..2047 pair with rows 2048..4095
static constexpr int NPOS = 4;
static constexpr int NNEG = 20;
static constexpr int NSEL = 24;
static constexpr int QPT1 = 8;      // int4 quads per thread per row (32 cols)

// Pre-filter threshold: top 1/128 of u32 (~128 candidates/row, need <=24;
// P(shortfall) ~ e^-73). Below-TH elements produce small nonzero "fake"
// comps (<= 32767) strictly below every real candidate; never popped.
// Exhausted threads are re-scanned exactly (no threshold) by the rebuild.
static constexpr uint32_t TH = 0xFE000000u;
// comp32 + OFF64 == full-range 64-bit comp (exact: TH's low 9 bits are 0)
static constexpr uint64_t OFF64 = ((uint64_t)(TH >> 9)) << 14;

__device__ __forceinline__ uint32_t rotl32(uint32_t x, int r) {
  return __builtin_amdgcn_alignbit(x, x, 32 - r);   // 1 instr
}

static constexpr uint32_t KS1 = 42u;
static constexpr uint32_t KS2 = 0x1BD11BDAu ^ 42u;   // ks0 = 0

// ---- JAX threefry2x32 (20 rounds), key = PRNGKey(42) = [0, 42] ----
__device__ __forceinline__ void tf2x32(uint32_t x0, uint32_t x1,
                                       uint32_t& o0, uint32_t& o1) {
  x1 += KS1;
#define TFR(r) { x0 += x1; x1 = rotl32(x1, (r)); x1 ^= x0; }
  TFR(13) TFR(15) TFR(26) TFR(6)
  x0 += KS1; x1 += KS2 + 1u;
  TFR(17) TFR(29) TFR(16) TFR(24)
  x0 += KS2; x1 += 2u;
  TFR(13) TFR(15) TFR(26) TFR(6)
  x1 += KS1 + 3u;
  TFR(17) TFR(29) TFR(16) TFR(24)
  x0 += KS1; x1 += KS2 + 4u;
  TFR(13) TFR(15) TFR(26) TFR(6)
  x0 += KS2; x1 += 5u;
#undef TFR
  o0 = x0; o1 = x1;
}

// 8 independent chains, round-interleaved (ILP=8). Chains 0-3: quad j
// (counter n0+k), chains 4-7: quad j+1 (n1 = n0 + 2048, 512-thread stride).
__device__ __forceinline__ void tf8(uint32_t n0, uint32_t n1,
                                    uint32_t (&oa)[8], uint32_t (&ob)[8]) {
  uint32_t x0[8], x1[8];
#pragma unroll
  for (int k = 0; k < 8; ++k) {
    const uint32_t n = (k < 4) ? (n0 + k) : (n1 + (k - 4));
    x0[k] = n; x1[k] = n + (0x2000000u + KS1);
  }
#define R8(r) { _Pragma("unroll") \
  for (int k = 0; k < 8; ++k) { x0[k] += x1[k]; x1[k] = rotl32(x1[k], (r)); x1[k] ^= x0[k]; } }
#define INJ8(a0, a1) { _Pragma("unroll") \
  for (int k = 0; k < 8; ++k) { x0[k] += (a0); x1[k] += (a1); } }
  R8(13) R8(15) R8(26) R8(6)
  INJ8(KS1, KS2 + 1u)
  R8(17) R8(29) R8(16) R8(24)
  INJ8(KS2, 2u)
  R8(13) R8(15) R8(26) R8(6)
  INJ8(0u, KS1 + 3u)
  R8(17) R8(29) R8(16) R8(24)
  INJ8(KS1, KS2 + 4u)
  R8(13) R8(15) R8(26) R8(6)
  INJ8(KS2, 5u)
#undef R8
#undef INJ8
#pragma unroll
  for (int k = 0; k < 8; ++k) { oa[k] = x0[k]; ob[k] = x1[k]; }
}

// full-range 64-bit composite key (rebuild path): larger = better; equal bits
// -> smaller col wins (jax top_k tie-break). Unique per row.
__device__ __forceinline__ uint64_t mkcomp(uint32_t bits, int c) {
  return (((uint64_t)(bits >> 9) + 1ull) << 14) | (uint64_t)(16383 - c);
}

// 6-op thresholded insert (bit-identical comps to the 7-op form; see r14).
__device__ __forceinline__ void filt_ins(uint32_t o, uint32_t KeAdj,
                                         uint32_t& a, uint32_t& b) {
  const uint32_t m  = (o > TH) ? o : TH;           // v_max_u32
  const uint32_t m2 = m & 0xFFFFFE00u;             // v_and
  const uint32_t comp = (m2 << 5) + KeAdj;         // v_lshl_add
  const uint32_t lo = comp < a ? comp : a;         // v_min
  a = comp > a ? comp : a;                         // v_max
  b = lo > b ? lo : b;                             // v_max
}

// Wave-synchronous top-20-negative selection over 512 depth-2 lists
// (8 lists per lane, statically indexed). Positives consumed-but-skipped.
// On list exhaustion (promotion wrote nxt=0), lanes 0..31 cooperatively
// rescan that thread's 32 columns (true comps, no threshold).
__device__ __forceinline__ void wave_select8(
    const uint32_t (*cd)[2], int* selX, int rbase, int hi, int4 p) {
  const int lane = threadIdx.x & 63;
  const int tb = lane << 3;
  const uint64_t laneu = (uint64_t)lane;
  uint64_t cur[8], nxt[8];
#pragma unroll
  for (int s = 0; s < 8; ++s) {
    cur[s] = (uint64_t)cd[tb + s][0] + OFF64;
    nxt[s] = (uint64_t)cd[tb + s][1] + OFF64;
  }
  int got = 0;
#pragma unroll 1
  for (int it = 0; it < NSEL && got < NNEG; ++it) {
    uint64_t m = 0;
#pragma unroll
    for (int s = 0; s < 8; ++s) {
      const uint64_t t = (cur[s] << 9) | ((uint64_t)s << 6) | laneu;
      if (t > m) m = t;
    }
#pragma unroll
    for (int o = 32; o; o >>= 1) {
      const uint64_t y = (uint64_t)__shfl_xor((unsigned long long)m, o, 64);
      if (y > m) m = y;
    }
    const int col = 16383 - (int)((m >> 9) & 0x3FFFull);
    const bool isPos = (col == p.x) || (col == p.y) || (col == p.z) || (col == p.w);
    if (!isPos) {
      if (lane == 0) selX[NPOS + got] = col;
      ++got;
    }
    const int owner = (int)(m & 63ull);
    const int slot  = (int)((m >> 6) & 7ull);
    const uint64_t bound = m >> 9;
    uint64_t mynxt = 0;
#pragma unroll
    for (int s = 0; s < 8; ++s) mynxt = (slot == s) ? nxt[s] : mynxt;
    const uint64_t ownnxt =
        (uint64_t)__shfl((unsigned long long)mynxt, owner, 64);
    uint64_t newv;
    if (ownnxt) {                        // wave-uniform: promote cached nxt
      newv = ownnxt;
    } else {                             // cooperative rebuild (rare)
      const int thr = (owner << 3) | slot;
      uint64_t v = 0;
      if (lane < 32) {
        const int col2 = ((lane >> 2) << 11) + (thr << 2) + (lane & 3);
        uint32_t o0, o1;
        tf2x32((uint32_t)(rbase + col2), (uint32_t)(rbase + col2) + 0x2000000u, o0, o1);
        v = mkcomp(hi ? o1 : o0, col2);
        if (v >= bound) v = 0;
      }
#pragma unroll
      for (int o = 32; o; o >>= 1) {
        const uint64_t y = (uint64_t)__shfl_xor((unsigned long long)v, o, 64);
        if (y > v) v = y;
      }
      newv = v;
    }
    if (lane == owner) {
#pragma unroll
      for (int s = 0; s < 8; ++s)
        if (slot == s) { cur[s] = newv; nxt[s] = 0; }
    }
  }
}

// ------- fused kernel: labels + hash + top-2 + select + sim + BCE -------
// Candidates hand off through LDS (no global round-trip, no extra launch).
__global__ __launch_bounds__(T1) void supcon_fused(
    const float* __restrict__ feat, const float* __restrict__ proto,
    const int* __restrict__ lab, float* __restrict__ row_ws) {
  __shared__ uint32_t candL[T1][2];
  __shared__ uint32_t candH[T1][2];
  __shared__ int selL[NSEL], selH[NSEL];
  __shared__ int posCnt[2];
  __shared__ int posBuf[2][4];
  __shared__ float ffL[D], ffH[D];
  __shared__ float normL, normH;
  __shared__ float bces[2 * NSEL];

  const int tid = threadIdx.x;
  const int r = blockIdx.x;
  const int rbase = r * C;

  if (tid < 2) posCnt[tid] = 0;
  __syncthreads();

  // ---- Phase A: stream labels, 8-wide hash, branchless 6-op top-2 ----
  const int4* labL4 = reinterpret_cast<const int4*>(lab + (size_t)rbase);
  const int4* labH4 = reinterpret_cast<const int4*>(lab + ((size_t)r + HALF) * C);
  uint32_t L0 = 0, L1 = 0, H0 = 0, H1 = 0;

#define CAP(V, S, CQ) \
  if (V.x | V.y | V.z | V.w) { \
    if (V.x) { int s = atomicAdd(&posCnt[S], 1); if (s < 4) posBuf[S][s] = (CQ); }     \
    if (V.y) { int s = atomicAdd(&posCnt[S], 1); if (s < 4) posBuf[S][s] = (CQ) + 1; } \
    if (V.z) { int s = atomicAdd(&posCnt[S], 1); if (s < 4) posBuf[S][s] = (CQ) + 2; } \
    if (V.w) { int s = atomicAdd(&posCnt[S], 1); if (s < 4) posBuf[S][s] = (CQ) + 3; } \
  }

#pragma unroll 1
  for (int j = 0; j < QPT1; j += 2) {
    const int4 vL0 = labL4[j * T1 + tid];
    const int4 vL1 = labL4[(j + 1) * T1 + tid];
    const int4 vH0 = labH4[j * T1 + tid];
    const int4 vH1 = labH4[(j + 1) * T1 + tid];
    const int cq0 = (j * T1 + tid) << 2;          // quad j; quad j+1 at +2048
    uint32_t oa[8], ob[8];
    tf8((uint32_t)(rbase + cq0), (uint32_t)(rbase + cq0 + 2048), oa, ob);
    const uint32_t ka0 = (32767u + 0x40000000u) - (uint32_t)cq0;  // KeAdj
    const uint32_t ka1 = ka0 - 2048u;
#pragma unroll
    for (int k = 0; k < 4; ++k) {
      filt_ins(oa[k],     ka0 - (uint32_t)k, L0, L1);
      filt_ins(oa[4 + k], ka1 - (uint32_t)k, L0, L1);
      filt_ins(ob[k],     ka0 - (uint32_t)k, H0, H1);
      filt_ins(ob[4 + k], ka1 - (uint32_t)k, H0, H1);
    }
    CAP(vL0, 0, cq0) CAP(vL1, 0, cq0 + 2048)
    CAP(vH0, 1, cq0) CAP(vH1, 1, cq0 + 2048)
  }
#undef CAP

  candL[tid][0] = L0; candL[tid][1] = L1;
  candH[tid][0] = H0; candH[tid][1] = H1;
  __syncthreads();
  if (tid < 2) {   // sort 4 positive cols ascending (jax top_k tie order)
    int a = posBuf[tid][0], b2 = posBuf[tid][1], c2 = posBuf[tid][2], d = posBuf[tid][3];
#define CSW(x, y) if (x > y) { int t_ = x; x = y; y = t_; }
    CSW(a, b2) CSW(c2, d) CSW(a, c2) CSW(b2, d) CSW(b2, c2)
#undef CSW
    int* s = tid ? selH : selL;
    s[0] = a; s[1] = b2; s[2] = c2; s[3] = d;
  }
  __syncthreads();

  // ---- Phase B: wave 0 selects L, wave 1 selects H, waves 2/3 norm ----
  const int wv = tid >> 6;
  if (wv == 0) {
    const int4 p = { selL[0], selL[1], selL[2], selL[3] };
    wave_select8(candL, selL, rbase, 0, p);
  } else if (wv == 1) {
    const int4 p = { selH[0], selH[1], selH[2], selH[3] };
    wave_select8(candH, selH, rbase, 1, p);
  } else if (wv == 2) {
    const int l = tid & 63;
    const float a = feat[(size_t)r * D + l];
    const float b = feat[(size_t)r * D + 64 + l];
    ffL[l] = a; ffL[64 + l] = b;
    float s = a * a + b * b;
#pragma unroll
    for (int o = 32; o; o >>= 1) s += __shfl_xor(s, o, 64);
    if (l == 0) normL = s;
  } else if (wv == 3) {
    const int l = tid & 63;
    const float a = feat[((size_t)r + HALF) * D + l];
    const float b = feat[((size_t)r + HALF) * D + 64 + l];
    ffH[l] = a; ffH[64 + l] = b;
    float s = a * a + b * b;
#pragma unroll
    for (int o = 32; o; o >>= 1) s += __shfl_xor(s, o, 64);
    if (l == 0) normH = s;
  }
  __syncthreads();

  // ---- Phase C: 48 selected columns x 4 lanes each -> sim + BCE ----
  if (tid < 4 * 2 * NSEL) {
    const int ci = tid >> 2;            // 0..47
    const int k  = tid & 3;
    const bool isH = ci >= NSEL;
    const int g = isH ? ci - NSEL : ci;
    const int c = isH ? selH[g] : selL[g];
    const float* ff = isH ? ffH : ffL;
    const float4* pc = reinterpret_cast<const float4*>(proto + (size_t)c * D);
    float fp = 0.f, pp = 0.f;
#pragma unroll
    for (int qq = 0; qq < 8; ++qq) {
      const float4 pv = pc[k * 8 + qq];
      const int d0 = k * 32 + qq * 4;
      fp += ff[d0] * pv.x + ff[d0 + 1] * pv.y + ff[d0 + 2] * pv.z + ff[d0 + 3] * pv.w;
      pp += pv.x * pv.x + pv.y * pv.y + pv.z * pv.z + pv.w * pv.w;
    }
    fp += __shfl_xor(fp, 1, 64); pp += __shfl_xor(pp, 1, 64);
    fp += __shfl_xor(fp, 2, 64); pp += __shfl_xor(pp, 2, 64);
    if (k == 0) {
      const float x = (isH ? normH : normL) * pp;
      float rn = rsqrtf(x);
      rn = rn * (1.5f - 0.5f * x * rn * rn);   // 1 NR step for accuracy
      const float l = fp * rn * 10.0f;          // /TEMP, TEMP=0.1
      const float tgt = (g < NPOS) ? 0.25f : 0.0f;
      bces[ci] = fmaxf(l, 0.f) - l * tgt + __logf(1.0f + __expf(-fabsf(l)));
    }
  }
  __syncthreads();
  if (tid < 2) {
    float s = 0.f;
    const int base = tid * NSEL;
#pragma unroll
    for (int i = 0; i < NSEL; ++i) s += bces[base + i];
    row_ws[tid ? (r + HALF) : r] = s * (1.0f / NSEL);
  }
}

__global__ __launch_bounds__(T2) void supcon_reduce(
    const float* __restrict__ ws, float* __restrict__ out) {
  __shared__ float red[T2];
  const int tid = threadIdx.x;
  float s = 0.f;
#pragma unroll
  for (int j = 0; j < BS / T2; ++j) s += ws[j * T2 + tid];
  red[tid] = s;
  __syncthreads();
  for (int o = T2 / 2; o > 0; o >>= 1) {
    if (tid < o) red[tid] += red[tid + o];
    __syncthreads();
  }
  if (tid == 0) out[0] = red[0] * (1.0f / BS);
}

extern "C" void kernel_launch(void* const* d_in, const int* in_sizes, int n_in,
                              void* d_out, int out_size, void* d_ws, size_t ws_size,
                              hipStream_t stream) {
  (void)in_sizes; (void)n_in; (void)out_size; (void)ws_size;
  const float* feat  = (const float*)d_in[0];
  const float* proto = (const float*)d_in[1];
  const int*   lab   = (const int*)d_in[2];
  float* out = (float*)d_out;
  float* ws  = (float*)d_ws;   // [0..4095]: per-row mean-BCE

  supcon_fused<<<dim3(HALF), dim3(T1), 0, stream>>>(feat, proto, lab, ws);
  supcon_reduce<<<dim3(1), dim3(T2), 0, stream>>>(ws, out);
}

// Round 16
// 84.028 us; speedup vs baseline: 3.1322x; 1.3542x over previous
//
#include <hip/hip_runtime.h>
#include <cstdint>

static constexpr int T1   = 512;    // fused kernel block size (8 waves)
static constexpr int T2   = 256;    // reduce kernel block size
static constexpr int BS   = 4096;
static constexpr int C    = 16384;
static constexpr int D    = 128;
static constexpr int HALF = 2048;   // rows 0..2047 pair with rows 2048..4095
static constexpr int NPOS = 4;
static constexpr int NNEG = 20;
static constexpr int NSEL = 24;
static constexpr int QPT1 = 8;      // int4 quads per thread per row (32 cols)
static constexpr int CAPN = 256;    // per-row candidate capacity (mean 128, +11sigma)

// Pre-filter threshold: top 1/128 of u32 -> ~128 candidates/row (need >=24
// incl. positives; P(shortfall) ~ e^-73). Compaction is LOSSLESS above TH,
// so selection is exact with no rebuild path.
static constexpr uint32_t TH = 0xFE000000u;

__device__ __forceinline__ uint32_t rotl32(uint32_t x, int r) {
  return __builtin_amdgcn_alignbit(x, x, 32 - r);   // 1 instr
}

__device__ __forceinline__ int mbcnt64(uint64_t m) {   // popc(mask & lt_lane)
  return (int)__builtin_amdgcn_mbcnt_hi((uint32_t)(m >> 32),
             __builtin_amdgcn_mbcnt_lo((uint32_t)m, 0u));
}

static constexpr uint32_t KS1 = 42u;
static constexpr uint32_t KS2 = 0x1BD11BDAu ^ 42u;   // ks0 = 0

// ---- JAX threefry2x32 (20 rounds), key = PRNGKey(42) = [0, 42] ----
// 8 independent chains, round-interleaved (ILP=8). Chains 0-3: quad j
// (counter n0+k), chains 4-7: quad j+1 (n1 = n0 + 2048, 512-thread stride).
__device__ __forceinline__ void tf8(uint32_t n0, uint32_t n1,
                                    uint32_t (&oa)[8], uint32_t (&ob)[8]) {
  uint32_t x0[8], x1[8];
#pragma unroll
  for (int k = 0; k < 8; ++k) {
    const uint32_t n = (k < 4) ? (n0 + k) : (n1 + (k - 4));
    x0[k] = n; x1[k] = n + (0x2000000u + KS1);
  }
#define R8(r) { _Pragma("unroll") \
  for (int k = 0; k < 8; ++k) { x0[k] += x1[k]; x1[k] = rotl32(x1[k], (r)); x1[k] ^= x0[k]; } }
#define INJ8(a0, a1) { _Pragma("unroll") \
  for (int k = 0; k < 8; ++k) { x0[k] += (a0); x1[k] += (a1); } }
  R8(13) R8(15) R8(26) R8(6)
  INJ8(KS1, KS2 + 1u)
  R8(17) R8(29) R8(16) R8(24)
  INJ8(KS2, 2u)
  R8(13) R8(15) R8(26) R8(6)
  INJ8(0u, KS1 + 3u)
  R8(17) R8(29) R8(16) R8(24)
  INJ8(KS1, KS2 + 4u)
  R8(13) R8(15) R8(26) R8(6)
  INJ8(KS2, 5u)
#undef R8
#undef INJ8
#pragma unroll
  for (int k = 0; k < 8; ++k) { oa[k] = x0[k]; ob[k] = x1[k]; }
}

// ---- fused kernel: labels + hash + compaction + set-select + sim + BCE ----
// comp32 for o >= TH: ((o & ~0x1FF) << 5) + KeAdj  ==  ((o-TH)>>9)<<14 + Ke
// (mod 2^32; KeAdj = Ke + 0x40000000, Ke = 32767-col). Low 14 bits = 16383-col
// (col recovery); comps distinct per row; larger = better, ties -> smaller col
// (matches jax top_k). comp < 2^31.
__global__ __launch_bounds__(T1) void supcon_fused(
    const float* __restrict__ feat, const float* __restrict__ proto,
    const int* __restrict__ lab, float* __restrict__ row_ws) {
  __shared__ uint32_t candArr[2][CAPN];
  __shared__ int candCnt[2];
  __shared__ int selL[NSEL], selH[NSEL];
  __shared__ int posCnt[2];
  __shared__ int posBuf[2][4];
  __shared__ float ffL[D], ffH[D];
  __shared__ float normL, normH;
  __shared__ float bces[2 * NSEL];

  const int tid = threadIdx.x;
  const int r = blockIdx.x;
  const int rbase = r * C;

  if (tid < 2) { posCnt[tid] = 0; candCnt[tid] = 0; }
  __syncthreads();

  // ---- Phase A: stream labels, 8-wide hash, compact above-TH comps ----
  const int4* labL4 = reinterpret_cast<const int4*>(lab + (size_t)rbase);
  const int4* labH4 = reinterpret_cast<const int4*>(lab + ((size_t)r + HALF) * C);

#define CAP(V, S, CQ) \
  if (V.x | V.y | V.z | V.w) { \
    if (V.x) { int s = atomicAdd(&posCnt[S], 1); if (s < 4) posBuf[S][s] = (CQ); }     \
    if (V.y) { int s = atomicAdd(&posCnt[S], 1); if (s < 4) posBuf[S][s] = (CQ) + 1; } \
    if (V.z) { int s = atomicAdd(&posCnt[S], 1); if (s < 4) posBuf[S][s] = (CQ) + 2; } \
    if (V.w) { int s = atomicAdd(&posCnt[S], 1); if (s < 4) posBuf[S][s] = (CQ) + 3; } \
  }

  // wave-aggregated LDS append (rare: P(lane) = 1/128)
#define APPEND(o, S, KA) \
  if ((o) >= TH) { \
    const uint32_t comp_ = (((o) & 0xFFFFFE00u) << 5) + (KA); \
    const uint64_t msk_ = __ballot(1); \
    const int pfx_ = mbcnt64(msk_); \
    int bse_ = 0; \
    if (pfx_ == 0) bse_ = atomicAdd(&candCnt[S], (int)__popcll(msk_)); \
    bse_ = __builtin_amdgcn_readfirstlane(bse_); \
    const int ix_ = bse_ + pfx_; \
    if (ix_ < CAPN) candArr[S][ix_] = comp_; \
  }

#pragma unroll 1
  for (int j = 0; j < QPT1; j += 2) {
    const int4 vL0 = labL4[j * T1 + tid];
    const int4 vL1 = labL4[(j + 1) * T1 + tid];
    const int4 vH0 = labH4[j * T1 + tid];
    const int4 vH1 = labH4[(j + 1) * T1 + tid];
    const int cq0 = (j * T1 + tid) << 2;          // quad j; quad j+1 at +2048
    uint32_t oa[8], ob[8];
    tf8((uint32_t)(rbase + cq0), (uint32_t)(rbase + cq0 + 2048), oa, ob);
    const uint32_t ka0 = (32767u + 0x40000000u) - (uint32_t)cq0;  // KeAdj
    const uint32_t ka1 = ka0 - 2048u;
#pragma unroll
    for (int k = 0; k < 4; ++k) {
      APPEND(oa[k],     0, ka0 - (uint32_t)k)
      APPEND(oa[4 + k], 0, ka1 - (uint32_t)k)
      APPEND(ob[k],     1, ka0 - (uint32_t)k)
      APPEND(ob[4 + k], 1, ka1 - (uint32_t)k)
    }
    CAP(vL0, 0, cq0) CAP(vL1, 0, cq0 + 2048)
    CAP(vH0, 1, cq0) CAP(vH1, 1, cq0 + 2048)
  }
#undef CAP
#undef APPEND

  __syncthreads();
  if (tid < 2) {   // sort 4 positive cols ascending (jax top_k tie order)
    int a = posBuf[tid][0], b2 = posBuf[tid][1], c2 = posBuf[tid][2], d = posBuf[tid][3];
#define CSW(x, y) if (x > y) { int t_ = x; x = y; y = t_; }
    CSW(a, b2) CSW(c2, d) CSW(a, c2) CSW(b2, d) CSW(b2, c2)
#undef CSW
    int* s = tid ? selH : selL;
    s[0] = a; s[1] = b2; s[2] = c2; s[3] = d;
  }
  __syncthreads();

  // ---- Phase B: waves 0/1 do exact top-20-set selection (radix descent);
  //      waves 2/3 load + normalize the two feature rows ----
  const int wv = tid >> 6;
  const int lane = tid & 63;
  if (wv < 2) {
    int* selX = wv ? selH : selL;
    const uint32_t* ca = candArr[wv];
    int n = candCnt[wv]; n = n < CAPN ? n : CAPN;
    const uint32_t ex0 = 16383u - (uint32_t)selX[0];
    const uint32_t ex1 = 16383u - (uint32_t)selX[1];
    const uint32_t ex2 = 16383u - (uint32_t)selX[2];
    const uint32_t ex3 = 16383u - (uint32_t)selX[3];
    uint32_t v0 = (lane       < n) ? ca[lane]       : 0u;
    uint32_t v1 = (lane + 64  < n) ? ca[lane + 64]  : 0u;
    uint32_t v2 = (lane + 128 < n) ? ca[lane + 128] : 0u;
    uint32_t v3 = (lane + 192 < n) ? ca[lane + 192] : 0u;
    // exclude positives by column match
#define EXCL(v) { const uint32_t a_ = (v) & 0x3FFFu; \
    if (a_ == ex0 || a_ == ex1 || a_ == ex2 || a_ == ex3) (v) = 0u; }
    EXCL(v0) EXCL(v1) EXCL(v2) EXCL(v3)
#undef EXCL
    // MSB radix descent: t_final = exact 20th-largest comp (values distinct)
    uint32_t t = 0;
#pragma unroll 1
    for (int b = 30; b >= 0; --b) {
      const uint32_t t2 = t | (1u << b);
      const int cnt = (int)__popcll(__ballot(v0 >= t2))
                    + (int)__popcll(__ballot(v1 >= t2))
                    + (int)__popcll(__ballot(v2 >= t2))
                    + (int)__popcll(__ballot(v3 >= t2));
      if (cnt >= NNEG) t = t2;
    }
    // emit the set {comp >= t} (exactly 20), mbcnt-prefix per slot
    int bse = NPOS;
    { const uint64_t m = __ballot(v0 >= t);
      if (v0 >= t) selX[bse + mbcnt64(m)] = 16383 - (int)(v0 & 0x3FFFu);
      bse += (int)__popcll(m); }
    { const uint64_t m = __ballot(v1 >= t);
      if (v1 >= t) selX[bse + mbcnt64(m)] = 16383 - (int)(v1 & 0x3FFFu);
      bse += (int)__popcll(m); }
    { const uint64_t m = __ballot(v2 >= t);
      if (v2 >= t) selX[bse + mbcnt64(m)] = 16383 - (int)(v2 & 0x3FFFu);
      bse += (int)__popcll(m); }
    { const uint64_t m = __ballot(v3 >= t);
      if (v3 >= t) selX[bse + mbcnt64(m)] = 16383 - (int)(v3 & 0x3FFFu);
      bse += (int)__popcll(m); }
    // canonicalize order (ascending col) -> deterministic across runs
    const int cmine = (lane < NNEG) ? selX[NPOS + lane] : 0x7FFFFFFF;
    int rank = 0;
#pragma unroll 1
    for (int jj = 0; jj < NNEG; ++jj) {
      const int cj = __shfl(cmine, jj, 64);
      rank += (cj < cmine) ? 1 : 0;
    }
    if (lane < NNEG) selX[NPOS + rank] = cmine;
  } else if (wv == 2) {
    const float a = feat[(size_t)r * D + lane];
    const float b = feat[(size_t)r * D + 64 + lane];
    ffL[lane] = a; ffL[64 + lane] = b;
    float s = a * a + b * b;
#pragma unroll
    for (int o = 32; o; o >>= 1) s += __shfl_xor(s, o, 64);
    if (lane == 0) normL = s;
  } else if (wv == 3) {
    const float a = feat[((size_t)r + HALF) * D + lane];
    const float b = feat[((size_t)r + HALF) * D + 64 + lane];
    ffH[lane] = a; ffH[64 + lane] = b;
    float s = a * a + b * b;
#pragma unroll
    for (int o = 32; o; o >>= 1) s += __shfl_xor(s, o, 64);
    if (lane == 0) normH = s;
  }
  __syncthreads();

  // ---- Phase C: 48 selected columns x 4 lanes each -> sim + BCE ----
  if (tid < 4 * 2 * NSEL) {
    const int ci = tid >> 2;            // 0..47
    const int k  = tid & 3;
    const bool isH = ci >= NSEL;
    const int g = isH ? ci - NSEL : ci;
    const int c = isH ? selH[g] : selL[g];
    const float* ff = isH ? ffH : ffL;
    const float4* pc = reinterpret_cast<const float4*>(proto + (size_t)c * D);
    float fp = 0.f, pp = 0.f;
#pragma unroll
    for (int qq = 0; qq < 8; ++qq) {
      const float4 pv = pc[k * 8 + qq];
      const int d0 = k * 32 + qq * 4;
      fp += ff[d0] * pv.x + ff[d0 + 1] * pv.y + ff[d0 + 2] * pv.z + ff[d0 + 3] * pv.w;
      pp += pv.x * pv.x + pv.y * pv.y + pv.z * pv.z + pv.w * pv.w;
    }
    fp += __shfl_xor(fp, 1, 64); pp += __shfl_xor(pp, 1, 64);
    fp += __shfl_xor(fp, 2, 64); pp += __shfl_xor(pp, 2, 64);
    if (k == 0) {
      const float x = (isH ? normH : normL) * pp;
      float rn = rsqrtf(x);
      rn = rn * (1.5f - 0.5f * x * rn * rn);   // 1 NR step for accuracy
      const float l = fp * rn * 10.0f;          // /TEMP, TEMP=0.1
      const float tgt = (g < NPOS) ? 0.25f : 0.0f;
      bces[ci] = fmaxf(l, 0.f) - l * tgt + __logf(1.0f + __expf(-fabsf(l)));
    }
  }
  __syncthreads();
  if (tid < 2) {
    float s = 0.f;
    const int base = tid * NSEL;
#pragma unroll
    for (int i = 0; i < NSEL; ++i) s += bces[base + i];
    row_ws[tid ? (r + HALF) : r] = s * (1.0f / NSEL);
  }
}

__global__ __launch_bounds__(T2) void supcon_reduce(
    const float* __restrict__ ws, float* __restrict__ out) {
  __shared__ float red[T2];
  const int tid = threadIdx.x;
  float s = 0.f;
#pragma unroll
  for (int j = 0; j < BS / T2; ++j) s += ws[j * T2 + tid];
  red[tid] = s;
  __syncthreads();
  for (int o = T2 / 2; o > 0; o >>= 1) {
    if (tid < o) red[tid] += red[tid + o];
    __syncthreads();
  }
  if (tid == 0) out[0] = red[0] * (1.0f / BS);
}

extern "C" void kernel_launch(void* const* d_in, const int* in_sizes, int n_in,
                              void* d_out, int out_size, void* d_ws, size_t ws_size,
                              hipStream_t stream) {
  (void)in_sizes; (void)n_in; (void)out_size; (void)ws_size;
  const float* feat  = (const float*)d_in[0];
  const float* proto = (const float*)d_in[1];
  const int*   lab   = (const int*)d_in[2];
  float* out = (float*)d_out;
  float* ws  = (float*)d_ws;   // [0..4095]: per-row mean-BCE

  supcon_fused<<<dim3(HALF), dim3(T1), 0, stream>>>(feat, proto, lab, ws);
  supcon_reduce<<<dim3(1), dim3(T2), 0, stream>>>(ws, out);
}